// Round 1
// baseline (530.453 us; speedup 1.0000x reference)
//
#include <hip/hip_runtime.h>

// Problem constants (match reference.py)
#define B_ 2
#define L_ 1024
#define M_ 8
#define N_ 16
#define C_ 16
#define H_ 64
#define W_ 64

#define NVOTE (M_ * N_)        // 128 votes per (b,l)
#define WPAD  (C_ + 1)         // pad weight rows to 17 floats -> no 32-way LDS bank conflict
#define PLANE (H_ * W_)        // 4096 floats per channel plane

__global__ __launch_bounds__(256) void hough_vote_kernel(
    const float* __restrict__ feats,       // [B,L,N,C] f32
    const int*   __restrict__ voxels_src,  // [B,L,2]   i32
    const int*   __restrict__ voxels_dst,  // [B,L,2]   i32
    const int*   __restrict__ idxs_src,    // [B,L,M]   i32
    const int*   __restrict__ idxs_dst,    // [B,L,N]   i32
    float*       __restrict__ out)         // [B,L,C,H,W] f32
{
    const int bl  = blockIdx.x;            // 0 .. B*L-1
    const int b   = bl >> 10;              // L == 1024
    const int tid = threadIdx.x;           // 0..255

    __shared__ int   s_src[M_];            // src KNN indices s[m]
    __shared__ int   s_bin[NVOTE];         // flattened bin per vote, -1 = invalid
    __shared__ float s_w[NVOTE * WPAD];    // vote weights, [vote][c] padded stride 17
    __shared__ float s_plane[PLANE];       // one channel's 64x64 histogram

    // ---- Phase 1a: load the M=8 src indices -------------------------------
    if (tid < M_) s_src[tid] = idxs_src[bl * M_ + tid];
    __syncthreads();

    // ---- Phase 1b: stage weights (128 votes x 16 ch = 2048 floats) --------
    // idx = i*256 + tid; for fixed i the 256 lanes read 256 contiguous floats
    // of feats[b, s[m], :, :] (N*C == 256) -> fully coalesced.
    #pragma unroll
    for (int i = 0; i < (NVOTE * C_) / 256; ++i) {
        int idx  = i * 256 + tid;          // 0..2047
        int m    = idx >> 8;               // 256 floats per m
        int off  = idx & 255;              // n*C + c
        int s    = s_src[m];
        float v  = feats[((size_t)(b * L_ + s)) * (N_ * C_) + off];
        int vote = (m << 4) | (off >> 4);  // m*N + n
        int c    = off & 15;
        s_w[vote * WPAD + c] = v;
    }

    // ---- Phase 1c: compute bins (threads 0..127, one per vote) ------------
    if (tid < NVOTE) {
        int m  = tid >> 4;                 // tid / N
        int n  = tid & 15;                 // tid % N
        int s  = s_src[m];
        int vy = voxels_src[(b * L_ + s) * 2 + 0];
        int vx = voxels_src[(b * L_ + s) * 2 + 1];
        int dd = idxs_dst[(b * L_ + s) * N_ + n];
        int dy = voxels_dst[(b * L_ + dd) * 2 + 0];
        int dx = voxels_dst[(b * L_ + dd) * 2 + 1];
        // voxels are ints: floor(float diff) == int diff exactly
        int by = dy - vy + H_ / 2;
        int bx = dx - vx + W_ / 2;
        bool valid = (by >= 0) & (by < H_) & (bx >= 0) & (bx < W_);
        s_bin[tid] = valid ? (by * W_ + bx) : -1;
    }
    __syncthreads();

    // ---- Phase 2: per-channel LDS histogram -> coalesced global store -----
    float*  outb = out + (size_t)bl * (C_ * PLANE);
    float4* p4   = (float4*)s_plane;

    for (int c = 0; c < C_; ++c) {
        // zero the plane (4096 floats = 1024 float4; 4 per thread)
        #pragma unroll
        for (int i = 0; i < PLANE / 4 / 256; ++i)
            p4[i * 256 + tid] = make_float4(0.f, 0.f, 0.f, 0.f);
        __syncthreads();

        // scatter the 128 votes (LDS atomics absorb bin collisions)
        if (tid < NVOTE) {
            int bin = s_bin[tid];
            if (bin >= 0) atomicAdd(&s_plane[bin], s_w[tid * WPAD + c]);
        }
        __syncthreads();

        // stream the plane to global: out[b,l,c,:,:], fully coalesced float4
        float4* o4 = (float4*)(outb + c * PLANE);
        #pragma unroll
        for (int i = 0; i < PLANE / 4 / 256; ++i)
            o4[i * 256 + tid] = p4[i * 256 + tid];
        __syncthreads();   // plane reused next channel
    }
}

extern "C" void kernel_launch(void* const* d_in, const int* in_sizes, int n_in,
                              void* d_out, int out_size, void* d_ws, size_t ws_size,
                              hipStream_t stream) {
    const float* feats      = (const float*)d_in[0];
    const int*   voxels_src = (const int*)d_in[1];
    const int*   voxels_dst = (const int*)d_in[2];
    const int*   idxs_src   = (const int*)d_in[3];
    const int*   idxs_dst   = (const int*)d_in[4];
    float*       out        = (float*)d_out;

    hough_vote_kernel<<<B_ * L_, 256, 0, stream>>>(
        feats, voxels_src, voxels_dst, idxs_src, idxs_dst, out);
}

// Round 2
// 527.236 us; speedup vs baseline: 1.0061x; 1.0061x over previous
//
#include <hip/hip_runtime.h>

// Problem constants (match reference.py)
#define B_ 2
#define L_ 1024
#define M_ 8
#define N_ 16
#define C_ 16
#define H_ 64
#define W_ 64

#define NVOTE (M_ * N_)        // 128 votes per (b,l)
#define PLANE (H_ * W_)        // 4096 floats per channel plane (16 KiB)

// One block per (b,l,c): build one channel plane in LDS, store it exactly once.
// Only 2 barriers per block, and NO barrier after the global store (fire-and-
// forget at endpgm) -> no vmcnt(0) drain serialization, unlike the previous
// per-channel-loop kernel (530 us, ~1 TB/s store rate from 48 barrier drains).
__global__ __launch_bounds__(256) void hough_vote_plane_kernel(
    const float* __restrict__ feats,       // [B,L,N,C] f32
    const int*   __restrict__ voxels_src,  // [B,L,2]   i32
    const int*   __restrict__ voxels_dst,  // [B,L,2]   i32
    const int*   __restrict__ idxs_src,    // [B,L,M]   i32
    const int*   __restrict__ idxs_dst,    // [B,L,N]   i32
    float*       __restrict__ out)         // [B,L,C,H,W] f32
{
    const int gb  = blockIdx.x;            // 0 .. B*L*C-1
    const int bl  = gb >> 4;               // (b*L + l)
    const int c   = gb & (C_ - 1);
    const int b   = bl >> 10;              // L == 1024
    const int tid = threadIdx.x;           // 0..255

    __shared__ float s_plane[PLANE];

    // ---- Vote computation: thread tid<128 owns vote (m,n) -----------------
    // Index/voxel/feat arrays total ~3 MB -> L2-resident; the 16 channel-
    // blocks per (b,l) redundantly recompute bins, which is cheap.
    float w   = 0.f;
    int   bin = -1;
    if (tid < NVOTE) {
        int m    = tid >> 4;               // tid / N
        int n    = tid & (N_ - 1);         // tid % N
        int s    = idxs_src[bl * M_ + m];
        int base = b * L_ + s;
        int2 vs  = ((const int2*)voxels_src)[base];
        int  dd  = idxs_dst[base * N_ + n];
        int2 vd  = ((const int2*)voxels_dst)[b * L_ + dd];
        // voxels are ints: floor(float diff) == int diff exactly
        int by = vd.x - vs.x + H_ / 2;
        int bx = vd.y - vs.y + W_ / 2;
        if (by >= 0 && by < H_ && bx >= 0 && bx < W_) {
            bin = by * W_ + bx;
            w   = feats[((size_t)base * N_ + n) * C_ + c];
        }
    }

    // ---- Zero the plane (overlaps with the gather loads above) ------------
    float4* p4 = (float4*)s_plane;
    #pragma unroll
    for (int i = 0; i < PLANE / 4 / 256; ++i)
        p4[i * 256 + tid] = make_float4(0.f, 0.f, 0.f, 0.f);
    __syncthreads();

    // ---- Scatter votes (LDS atomics absorb bin collisions) ----------------
    if (bin >= 0) atomicAdd(&s_plane[bin], w);
    __syncthreads();

    // ---- Store the plane: out[b,l,c,:,:], coalesced float4, no barrier ----
    float4* o4 = (float4*)(out + ((size_t)bl * C_ + c) * PLANE);
    #pragma unroll
    for (int i = 0; i < PLANE / 4 / 256; ++i)
        o4[i * 256 + tid] = p4[i * 256 + tid];
}

extern "C" void kernel_launch(void* const* d_in, const int* in_sizes, int n_in,
                              void* d_out, int out_size, void* d_ws, size_t ws_size,
                              hipStream_t stream) {
    const float* feats      = (const float*)d_in[0];
    const int*   voxels_src = (const int*)d_in[1];
    const int*   voxels_dst = (const int*)d_in[2];
    const int*   idxs_src   = (const int*)d_in[3];
    const int*   idxs_dst   = (const int*)d_in[4];
    float*       out        = (float*)d_out;

    hough_vote_plane_kernel<<<B_ * L_ * C_, 256, 0, stream>>>(
        feats, voxels_src, voxels_dst, idxs_src, idxs_dst, out);
}